// Round 1
// baseline (189.900 us; speedup 1.0000x reference)
//
#include <hip/hip_runtime.h>
#include <cstdint>
#include <cstddef>

// ---------------------------------------------------------------------------
// DeMash = complex GEMM: out[bts, m] = sum_l y[bts, l] * conj(C)[m, l]
//   out_r = Yr@Cr^T + Yi@Ci^T ; out_i = Yi@Cr^T - Yr@Ci^T
// Reformulated as one real NT GEMM:
//   A [M=2048, K=3072]  row-major fp16  (K: [Yr(1512) | Yi(1512) | 0-pad])
//   W [N=3072, K=3072]  row-major fp16  (rows n<1512: [Cr|Ci|0];
//                                        rows 1512..3023: [-Ci|Cr|0]; rest 0)
//   Out[m, n] = sum_k A[m,k] * W[n,k]   -> scattered into [2,2048,14,128]
// ---------------------------------------------------------------------------

typedef _Float16 half_t;
typedef half_t half8 __attribute__((ext_vector_type(8)));
typedef half_t half2_t __attribute__((ext_vector_type(2)));
typedef float floatx4 __attribute__((ext_vector_type(4)));

#define M_DIM 2048
#define N_DIM 3072
#define K_DIM 3072
#define LDIM 1512
#define NSC 108
#define SYMS 14
#define FFT 128
#define ROWLEN (SYMS * FFT)   // 1792

#define BM 128
#define BN 128
#define BK 32

typedef __attribute__((address_space(3))) uint32_t lds_u32_t;
typedef const __attribute__((address_space(1))) uint32_t glob_u32_t;

__device__ __forceinline__ void gl2lds16(const void* g, void* l) {
    // async global->LDS, 16B per lane; LDS dest must be wave-uniform base + lane*16
    __builtin_amdgcn_global_load_lds((glob_u32_t*)g, (lds_u32_t*)l, 16, 0, 0);
}

// ---------------------------------------------------------------------------
// prep_x: gather effective subcarriers, convert fp32->fp16, build A
// one thread -> 2 consecutive k (packed 4B store). grid: 2048*1536/256
// ---------------------------------------------------------------------------
__global__ __launch_bounds__(256) void prep_x(
    const float* __restrict__ xr, const float* __restrict__ xi,
    const int* __restrict__ sc, half_t* __restrict__ A)
{
    int idx = blockIdx.x * 256 + threadIdx.x;      // [0, 2048*1536)
    int row = idx / 1536;
    int kk = (idx - row * 1536) * 2;
    half_t v[2];
#pragma unroll
    for (int e = 0; e < 2; ++e) {
        int k = kk + e;
        float f = 0.0f;
        if (k < LDIM) {
            int sym = k / NSC;
            int j = k - sym * NSC;
            f = xr[(size_t)row * ROWLEN + sym * FFT + sc[j]];
        } else if (k < 2 * LDIM) {
            int k2 = k - LDIM;
            int sym = k2 / NSC;
            int j = k2 - sym * NSC;
            f = xi[(size_t)row * ROWLEN + sym * FFT + sc[j]];
        }
        v[e] = (half_t)f;
    }
    half2_t p = {v[0], v[1]};
    *(half2_t*)(A + (size_t)row * K_DIM + kk) = p;
}

// ---------------------------------------------------------------------------
// prep_w: build W with conj sign folded in. grid: 3072*1536/256
// ---------------------------------------------------------------------------
__global__ __launch_bounds__(256) void prep_w(
    const float* __restrict__ Cr, const float* __restrict__ Ci,
    half_t* __restrict__ W)
{
    int idx = blockIdx.x * 256 + threadIdx.x;      // [0, 3072*1536)
    int n = idx / 1536;
    int kk = (idx - n * 1536) * 2;
    half_t v[2];
#pragma unroll
    for (int e = 0; e < 2; ++e) {
        int k = kk + e;
        float f = 0.0f;
        if (n < LDIM) {
            if (k < LDIM)            f = Cr[(size_t)n * LDIM + k];
            else if (k < 2 * LDIM)   f = Ci[(size_t)n * LDIM + (k - LDIM)];
        } else if (n < 2 * LDIM) {
            int m = n - LDIM;
            if (k < LDIM)            f = -Ci[(size_t)m * LDIM + k];
            else if (k < 2 * LDIM)   f = Cr[(size_t)m * LDIM + (k - LDIM)];
        }
        v[e] = (half_t)f;
    }
    half2_t p = {v[0], v[1]};
    *(half2_t*)(W + (size_t)n * K_DIM + kk) = p;
}

// ---------------------------------------------------------------------------
// gemm_scatter: 128x128 tile, BK=32, 4 waves, 4x4 mfma_f32_16x16x32_f16/wave,
// global_load_lds width-16 staging, epilogue scatters directly into out grid.
// grid: (N_DIM/BN, M_DIM/BM) = (24, 16), block 256
// ---------------------------------------------------------------------------
__global__ __launch_bounds__(256) void gemm_scatter(
    const half_t* __restrict__ A,   // [M_DIM][K_DIM]
    const half_t* __restrict__ W,   // [N_DIM][K_DIM]
    const int* __restrict__ sc,
    float* __restrict__ out)        // [2][2048][14][128], pre-zeroed
{
    __shared__ __align__(16) half_t As[BM * BK];
    __shared__ __align__(16) half_t Bs[BN * BK];

    const int t = threadIdx.x;
    const int bn = blockIdx.x;
    const int bm = blockIdx.y;
    const int lane = t & 63;
    const int wave = t >> 6;
    const int wm = (wave & 1) * 64;   // wave's M offset in tile
    const int wn = (wave >> 1) * 64;  // wave's N offset in tile

    floatx4 acc[4][4] = {};

    // staging: chunk c = issue*256 + t -> tile row c>>2, k-chunk (c&3)*8
    const int srow = t >> 2;
    const int skc = (t & 3) * 8;
    const half_t* gA = A + (size_t)(bm * BM + srow) * K_DIM + skc;
    const half_t* gB = W + (size_t)(bn * BN + srow) * K_DIM + skc;
    half_t* lA = As + t * 8;          // = base + lane*16B pattern per wave
    half_t* lB = Bs + t * 8;

    const int fr = lane & 15;         // fragment row/col within 16
    const int fq = (lane >> 4) * 8;   // k quad offset

    for (int kb = 0; kb < K_DIM / BK; ++kb) {
        __syncthreads();
        const half_t* ga = gA + kb * BK;
        const half_t* gb = gB + kb * BK;
        gl2lds16(ga, lA);
        gl2lds16(ga + (size_t)64 * K_DIM, lA + 64 * BK);
        gl2lds16(gb, lB);
        gl2lds16(gb + (size_t)64 * K_DIM, lB + 64 * BK);
        __syncthreads();

        half8 af[4], bf[4];
#pragma unroll
        for (int i = 0; i < 4; ++i) {
            af[i] = *(const half8*)&As[(wm + i * 16 + fr) * BK + fq];
            bf[i] = *(const half8*)&Bs[(wn + i * 16 + fr) * BK + fq];
        }
#pragma unroll
        for (int i = 0; i < 4; ++i)
#pragma unroll
            for (int j = 0; j < 4; ++j)
                acc[i][j] = __builtin_amdgcn_mfma_f32_16x16x32_f16(
                    af[i], bf[j], acc[i][j], 0, 0, 0);
    }

    // epilogue: C/D layout col = lane&15 (N), row = (lane>>4)*4 + reg (M)
    const int col_base = bn * BN + wn + (lane & 15);
    const int row_base = bm * BM + wm + ((lane >> 4) * 4);
#pragma unroll
    for (int j = 0; j < 4; ++j) {
        int n = col_base + j * 16;
        if (n >= 2 * LDIM) continue;          // N-pad region: discard
        int ri = (n >= LDIM) ? 1 : 0;
        int nn = n - ri * LDIM;
        int sym = nn / NSC;
        int jj = nn - sym * NSC;
        size_t colOff = (size_t)ri * (M_DIM * ROWLEN) + sym * FFT + sc[jj];
#pragma unroll
        for (int i = 0; i < 4; ++i) {
            int row0 = row_base + i * 16;
#pragma unroll
            for (int r = 0; r < 4; ++r) {
                out[colOff + (size_t)(row0 + r) * ROWLEN] = acc[i][j][r];
            }
        }
    }
}

// ---------------------------------------------------------------------------
extern "C" void kernel_launch(void* const* d_in, const int* in_sizes, int n_in,
                              void* d_out, int out_size, void* d_ws, size_t ws_size,
                              hipStream_t stream) {
    const float* xr = (const float*)d_in[0];
    const float* xi = (const float*)d_in[1];
    const float* Cr = (const float*)d_in[2];
    const float* Ci = (const float*)d_in[3];
    const int* sc   = (const int*)d_in[4];
    float* out = (float*)d_out;

    half_t* Ah = (half_t*)d_ws;                                    // 12.58 MB
    half_t* Wh = (half_t*)((char*)d_ws + (size_t)M_DIM * K_DIM * 2); // 18.87 MB

    // zero the full output grid (guard subcarriers must be 0; d_out is poisoned)
    hipMemsetAsync(d_out, 0, (size_t)out_size * sizeof(float), stream);

    prep_x<<<(M_DIM * (K_DIM / 2)) / 256, 256, 0, stream>>>(xr, xi, sc, Ah);
    prep_w<<<(N_DIM * (K_DIM / 2)) / 256, 256, 0, stream>>>(Cr, Ci, Wh);

    dim3 grid(N_DIM / BN, M_DIM / BM);   // (24, 16)
    gemm_scatter<<<grid, 256, 0, stream>>>(Ah, Wh, sc, out);
}

// Round 2
// 180.613 us; speedup vs baseline: 1.0514x; 1.0514x over previous
//
#include <hip/hip_runtime.h>
#include <cstdint>
#include <cstddef>

// ---------------------------------------------------------------------------
// DeMash = complex GEMM: out[bts, m] = sum_l y[bts, l] * conj(C)[m, l]
//   out_r = Yr@Cr^T + Yi@Ci^T ; out_i = Yi@Cr^T - Yr@Ci^T
// One real NT GEMM:
//   A [M=2048, K=3072] row-major fp16  (K: [Yr(1512) | Yi(1512) | 0-pad])
//   W [N=3072, K=3072] row-major fp16  (n<1512: [Cr|Ci|0]; 1512..3023:
//                                       [-Ci|Cr|0]; rest 0)
//   Out[m, n] = sum_k A[m,k] * W[n,k] -> scattered into [2,2048,14,128]
//
// R2: BM=64,BN=128 -> grid 768 = 3 blocks/CU (was 384 = 1.5/CU, occupancy-
// limited at MfmaUtil 20%). Prep fused to ONE dispatch; guard-only zeroing
// replaces full-grid memset.
// ---------------------------------------------------------------------------

typedef _Float16 half_t;
typedef half_t half8 __attribute__((ext_vector_type(8)));
typedef float floatx4 __attribute__((ext_vector_type(4)));

#define M_DIM 2048
#define N_DIM 3072
#define K_DIM 3072
#define LDIM 1512
#define NSC 108
#define SYMS 14
#define FFT 128
#define ROWLEN (SYMS * FFT)   // 1792

#define BM 64
#define BN 128
#define BK 32

// prep grid partition (blocks of 256 threads)
#define PA_BLOCKS 3072   // A: 2048*3072/8/256, 8 halfs (16B) per thread
#define PW_BLOCKS 4608   // W: 3072*3072/8/256
#define PG_BLOCKS 4480   // guard zero: 2*2048*14*20/256

typedef __attribute__((address_space(3))) uint32_t lds_u32_t;
typedef const __attribute__((address_space(1))) uint32_t glob_u32_t;

__device__ __forceinline__ void gl2lds16(const void* g, void* l) {
    __builtin_amdgcn_global_load_lds((glob_u32_t*)g, (lds_u32_t*)l, 16, 0, 0);
}

// ---------------------------------------------------------------------------
// prep_all: one dispatch does A-build, W-build, guard zeroing (branch is
// wave-uniform on blockIdx). 1512 and 3024 are multiples of 8, so every
// 8-element chunk lies in a single source region.
// ---------------------------------------------------------------------------
__global__ __launch_bounds__(256) void prep_all(
    const float* __restrict__ xr, const float* __restrict__ xi,
    const float* __restrict__ Cr, const float* __restrict__ Ci,
    const int* __restrict__ sc,
    half_t* __restrict__ A, half_t* __restrict__ W, float* __restrict__ out)
{
    const int b = blockIdx.x;
    const int t = threadIdx.x;

    if (b < PA_BLOCKS) {
        int idx = b * 256 + t;                 // [0, 2048*384)
        int row = idx / 384;
        int k0 = (idx - row * 384) * 8;
        half_t v[8];
        const float* src = nullptr;
        int kb = k0;
        if (k0 < LDIM)            { src = xr; }
        else if (k0 < 2 * LDIM)   { src = xi; kb = k0 - LDIM; }
        if (src) {
            const float* rowp = src + (size_t)row * ROWLEN;
#pragma unroll
            for (int e = 0; e < 8; ++e) {
                int k = kb + e;
                int sym = k / NSC;
                int j = k - sym * NSC;
                v[e] = (half_t)rowp[sym * FFT + sc[j]];
            }
        } else {
#pragma unroll
            for (int e = 0; e < 8; ++e) v[e] = (half_t)0.0f;
        }
        *(half8*)(A + (size_t)row * K_DIM + k0) = *(half8*)v;
    } else if (b < PA_BLOCKS + PW_BLOCKS) {
        int idx = (b - PA_BLOCKS) * 256 + t;   // [0, 3072*384)
        int n = idx / 384;
        int k0 = (idx - n * 384) * 8;
        half_t v[8];
        const float* src = nullptr;
        float sgn = 1.0f;
        int nn = n, kb = k0;
        if (n < LDIM) {
            if (k0 < LDIM)            { src = Cr; }
            else if (k0 < 2 * LDIM)   { src = Ci; kb = k0 - LDIM; }
        } else if (n < 2 * LDIM) {
            nn = n - LDIM;
            if (k0 < LDIM)            { src = Ci; sgn = -1.0f; }
            else if (k0 < 2 * LDIM)   { src = Cr; kb = k0 - LDIM; }
        }
        if (src) {
            const float* rowp = src + (size_t)nn * LDIM + kb;
#pragma unroll
            for (int e = 0; e < 8; ++e) v[e] = (half_t)(sgn * rowp[e]);
        } else {
#pragma unroll
            for (int e = 0; e < 8; ++e) v[e] = (half_t)0.0f;
        }
        *(half8*)(W + (size_t)n * K_DIM + k0) = *(half8*)v;
    } else {
        // zero guard columns [0,10) U [118,128) for all 4096 rows x 14 syms
        int idx = (b - PA_BLOCKS - PW_BLOCKS) * 256 + t;  // [0, 1146880)
        int c20 = idx % 20;
        int rest = idx / 20;
        int sym = rest % 14;
        int rowri = rest / 14;                 // [0, 4096) covers both ri
        int col = (c20 < 10) ? c20 : (NSC + c20);
        out[(size_t)rowri * ROWLEN + sym * FFT + col] = 0.0f;
    }
}

// ---------------------------------------------------------------------------
// gemm_scatter: 64x128 tile, BK=32, 4 waves, each wave 64Mx32N via 4x2
// mfma_f32_16x16x32_f16. grid (24, 32) = 768 blocks = 3/CU.
// ---------------------------------------------------------------------------
__global__ __launch_bounds__(256) void gemm_scatter(
    const half_t* __restrict__ A,   // [M_DIM][K_DIM]
    const half_t* __restrict__ W,   // [N_DIM][K_DIM]
    const int* __restrict__ sc,
    float* __restrict__ out)        // [2][2048][14][128]; guards pre-zeroed
{
    __shared__ __align__(16) half_t As[BM * BK];   // 4 KB
    __shared__ __align__(16) half_t Bs[BN * BK];   // 8 KB

    const int t = threadIdx.x;
    const int bn = blockIdx.x;
    const int bm = blockIdx.y;
    const int lane = t & 63;
    const int wave = t >> 6;
    const int wn = wave * 32;         // wave's N offset in tile

    floatx4 acc[4][2] = {};

    // staging: thread t -> tile row t>>2, k-chunk (t&3)*8
    const int srow = t >> 2;
    const int skc = (t & 3) * 8;
    const half_t* gA = A + (size_t)(bm * BM + srow) * K_DIM + skc;
    const half_t* gB = W + (size_t)(bn * BN + srow) * K_DIM + skc;
    half_t* lA = As + t * 8;
    half_t* lB = Bs + t * 8;

    const int fr = lane & 15;
    const int fq = (lane >> 4) * 8;

    for (int kb = 0; kb < K_DIM / BK; ++kb) {
        __syncthreads();
        gl2lds16(gA + kb * BK, lA);
        gl2lds16(gB + kb * BK, lB);
        gl2lds16(gB + (size_t)64 * K_DIM + kb * BK, lB + 64 * BK);
        __syncthreads();

        half8 af[4], bf[2];
#pragma unroll
        for (int i = 0; i < 4; ++i)
            af[i] = *(const half8*)&As[(i * 16 + fr) * BK + fq];
#pragma unroll
        for (int j = 0; j < 2; ++j)
            bf[j] = *(const half8*)&Bs[(wn + j * 16 + fr) * BK + fq];
#pragma unroll
        for (int i = 0; i < 4; ++i)
#pragma unroll
            for (int j = 0; j < 2; ++j)
                acc[i][j] = __builtin_amdgcn_mfma_f32_16x16x32_f16(
                    af[i], bf[j], acc[i][j], 0, 0, 0);
    }

    // epilogue: C/D layout col = lane&15 (N), row = (lane>>4)*4 + reg (M)
    const int col_base = bn * BN + wn + (lane & 15);
    const int row_base = bm * BM + ((lane >> 4) * 4);
#pragma unroll
    for (int j = 0; j < 2; ++j) {
        int n = col_base + j * 16;
        if (n >= 2 * LDIM) continue;           // N-pad region: discard
        int ri = (n >= LDIM) ? 1 : 0;
        int nn = n - ri * LDIM;
        int sym = nn / NSC;
        int jj = nn - sym * NSC;
        size_t colOff = (size_t)ri * (M_DIM * ROWLEN) + sym * FFT + sc[jj];
#pragma unroll
        for (int i = 0; i < 4; ++i) {
            int row0 = row_base + i * 16;
#pragma unroll
            for (int r = 0; r < 4; ++r) {
                out[colOff + (size_t)(row0 + r) * ROWLEN] = acc[i][j][r];
            }
        }
    }
}

// ---------------------------------------------------------------------------
extern "C" void kernel_launch(void* const* d_in, const int* in_sizes, int n_in,
                              void* d_out, int out_size, void* d_ws, size_t ws_size,
                              hipStream_t stream) {
    const float* xr = (const float*)d_in[0];
    const float* xi = (const float*)d_in[1];
    const float* Cr = (const float*)d_in[2];
    const float* Ci = (const float*)d_in[3];
    const int* sc   = (const int*)d_in[4];
    float* out = (float*)d_out;

    half_t* Ah = (half_t*)d_ws;                                      // 12.58 MB
    half_t* Wh = (half_t*)((char*)d_ws + (size_t)M_DIM * K_DIM * 2); // 18.87 MB

    prep_all<<<PA_BLOCKS + PW_BLOCKS + PG_BLOCKS, 256, 0, stream>>>(
        xr, xi, Cr, Ci, sc, Ah, Wh, out);

    dim3 grid(N_DIM / BN, M_DIM / BM);   // (24, 32) = 768 blocks
    gemm_scatter<<<grid, 256, 0, stream>>>(Ah, Wh, sc, out);
}

// Round 3
// 160.861 us; speedup vs baseline: 1.1805x; 1.1228x over previous
//
#include <hip/hip_runtime.h>
#include <cstdint>
#include <cstddef>

// ---------------------------------------------------------------------------
// DeMash = complex GEMM: out[bts, m] = sum_l y[bts, l] * conj(C)[m, l]
//   out_r = Yr@Cr^T + Yi@Ci^T ; out_i = Yi@Cr^T - Yr@Ci^T
// One real NT GEMM:
//   A [M=2048, K=3072] row-major fp16  (K: [Yr(1512) | Yi(1512) | 0-pad])
//   W [N=3072, K=3072] row-major fp16  (n<1512: [Cr|Ci|0]; 1512..3023:
//                                       [-Ci|Cr|0]; rest 0)
//   Out[m, n] = sum_k A[m,k] * W[n,k] -> scattered into [2,2048,14,128]
//
// R3: R2's MfmaUtil was pinned at 19% by 8-way LDS bank conflicts
// (SQ_LDS_BANK_CONFLICT 7.08M; row stride 64B -> lanes 0..15 alias 2 bank
// quads). Fix: BK=64 (row stride 128B = bank-aligned) + XOR chunk swizzle
// slot = kchunk ^ (row&7), applied on the GLOBAL source address so
// global_load_lds keeps its mandatory base+lane*16 contiguous LDS dest.
// Also halves barrier count (96 -> 48 iters).
// ---------------------------------------------------------------------------

typedef _Float16 half_t;
typedef half_t half8 __attribute__((ext_vector_type(8)));
typedef float floatx4 __attribute__((ext_vector_type(4)));

#define M_DIM 2048
#define N_DIM 3072
#define K_DIM 3072
#define LDIM 1512
#define NSC 108
#define SYMS 14
#define FFT 128
#define ROWLEN (SYMS * FFT)   // 1792

#define BM 64
#define BN 128
#define BK 64

// prep grid partition (blocks of 256 threads)
#define PA_BLOCKS 3072   // A: 2048*3072/8/256, 8 halfs (16B) per thread
#define PW_BLOCKS 4608   // W: 3072*3072/8/256
#define PG_BLOCKS 4480   // guard zero: 2*2048*14*20/256

typedef __attribute__((address_space(3))) uint32_t lds_u32_t;
typedef const __attribute__((address_space(1))) uint32_t glob_u32_t;

__device__ __forceinline__ void gl2lds16(const void* g, void* l) {
    __builtin_amdgcn_global_load_lds((glob_u32_t*)g, (lds_u32_t*)l, 16, 0, 0);
}

// ---------------------------------------------------------------------------
// prep_all: one dispatch does A-build, W-build, guard zeroing (branch is
// wave-uniform on blockIdx). 1512 and 3024 are multiples of 8, so every
// 8-element chunk lies in a single source region.
// ---------------------------------------------------------------------------
__global__ __launch_bounds__(256) void prep_all(
    const float* __restrict__ xr, const float* __restrict__ xi,
    const float* __restrict__ Cr, const float* __restrict__ Ci,
    const int* __restrict__ sc,
    half_t* __restrict__ A, half_t* __restrict__ W, float* __restrict__ out)
{
    const int b = blockIdx.x;
    const int t = threadIdx.x;

    if (b < PA_BLOCKS) {
        int idx = b * 256 + t;                 // [0, 2048*384)
        int row = idx / 384;
        int k0 = (idx - row * 384) * 8;
        half_t v[8];
        const float* src = nullptr;
        int kb = k0;
        if (k0 < LDIM)            { src = xr; }
        else if (k0 < 2 * LDIM)   { src = xi; kb = k0 - LDIM; }
        if (src) {
            const float* rowp = src + (size_t)row * ROWLEN;
#pragma unroll
            for (int e = 0; e < 8; ++e) {
                int k = kb + e;
                int sym = k / NSC;
                int j = k - sym * NSC;
                v[e] = (half_t)rowp[sym * FFT + sc[j]];
            }
        } else {
#pragma unroll
            for (int e = 0; e < 8; ++e) v[e] = (half_t)0.0f;
        }
        *(half8*)(A + (size_t)row * K_DIM + k0) = *(half8*)v;
    } else if (b < PA_BLOCKS + PW_BLOCKS) {
        int idx = (b - PA_BLOCKS) * 256 + t;   // [0, 3072*384)
        int n = idx / 384;
        int k0 = (idx - n * 384) * 8;
        half_t v[8];
        const float* src = nullptr;
        float sgn = 1.0f;
        int nn = n, kb = k0;
        if (n < LDIM) {
            if (k0 < LDIM)            { src = Cr; }
            else if (k0 < 2 * LDIM)   { src = Ci; kb = k0 - LDIM; }
        } else if (n < 2 * LDIM) {
            nn = n - LDIM;
            if (k0 < LDIM)            { src = Ci; sgn = -1.0f; }
            else if (k0 < 2 * LDIM)   { src = Cr; kb = k0 - LDIM; }
        }
        if (src) {
            const float* rowp = src + (size_t)nn * LDIM + kb;
#pragma unroll
            for (int e = 0; e < 8; ++e) v[e] = (half_t)(sgn * rowp[e]);
        } else {
#pragma unroll
            for (int e = 0; e < 8; ++e) v[e] = (half_t)0.0f;
        }
        *(half8*)(W + (size_t)n * K_DIM + k0) = *(half8*)v;
    } else {
        // zero guard columns [0,10) U [118,128) for all 4096 rows x 14 syms
        int idx = (b - PA_BLOCKS - PW_BLOCKS) * 256 + t;  // [0, 1146880)
        int c20 = idx % 20;
        int rest = idx / 20;
        int sym = rest % 14;
        int rowri = rest / 14;                 // [0, 4096) covers both ri
        int col = (c20 < 10) ? c20 : (NSC + c20);
        out[(size_t)rowri * ROWLEN + sym * FFT + col] = 0.0f;
    }
}

// ---------------------------------------------------------------------------
// gemm_scatter: 64x128 tile, BK=64, 4 waves, each wave 64Mx32N via 4x2
// mfma_f32_16x16x32_f16 x 2 k-steps. grid (24, 32) = 768 blocks = 3/CU.
// LDS layout: As[64 rows][8 chunks], Bs[128][8]; chunk = 16B (8 halfs).
// Physical slot p of row r holds global k-chunk p ^ (r&7)  (bank swizzle).
// ---------------------------------------------------------------------------
__global__ __launch_bounds__(256) void gemm_scatter(
    const half_t* __restrict__ A,   // [M_DIM][K_DIM]
    const half_t* __restrict__ W,   // [N_DIM][K_DIM]
    const int* __restrict__ sc,
    float* __restrict__ out)        // [2][2048][14][128]; guards pre-zeroed
{
    __shared__ __align__(16) half_t As[BM * BK];   // 8 KB
    __shared__ __align__(16) half_t Bs[BN * BK];   // 16 KB

    const int t = threadIdx.x;
    const int bn = blockIdx.x;
    const int bm = blockIdx.y;
    const int lane = t & 63;
    const int wn = (t >> 6) * 32;     // wave's N offset in tile

    floatx4 acc[4][2] = {};

    // ---- staging setup: chunk c (16B): row = c>>3, slot = c&7,
    //      global k-chunk g = slot ^ (row&7). LDS dest = base + c*16
    //      (contiguous in lane => legal global_load_lds dest).
    const half_t* gAp[2];
    const half_t* gBp[4];
    half_t* lAp[2];
    half_t* lBp[4];
#pragma unroll
    for (int r = 0; r < 2; ++r) {
        int c = r * 256 + t;
        int row = c >> 3, slot = c & 7;
        int g = slot ^ (row & 7);
        gAp[r] = A + (size_t)(bm * BM + row) * K_DIM + g * 8;
        lAp[r] = As + c * 8;
    }
#pragma unroll
    for (int r = 0; r < 4; ++r) {
        int c = r * 256 + t;
        int row = c >> 3, slot = c & 7;
        int g = slot ^ (row & 7);
        gBp[r] = W + (size_t)(bn * BN + row) * K_DIM + g * 8;
        lBp[r] = Bs + c * 8;
    }

    const int fr = lane & 15;         // fragment row (M or N within 16)
    const int cr = lane >> 4;         // k-quad index within a 32-k step
    // swizzled slot for k-step s: (s*4 + cr) ^ (fr&7)  (row&7 == fr&7 since
    // row = i*16 + fr and 16 ≡ 0 mod 8)
    const int slot0 = (cr) ^ (fr & 7);
    const int slot1 = (4 + cr) ^ (fr & 7);

    for (int kb = 0; kb < K_DIM / BK; ++kb) {
        __syncthreads();
        gl2lds16(gAp[0], lAp[0]);
        gl2lds16(gAp[1], lAp[1]);
        gl2lds16(gBp[0], lBp[0]);
        gl2lds16(gBp[1], lBp[1]);
        gl2lds16(gBp[2], lBp[2]);
        gl2lds16(gBp[3], lBp[3]);
        gAp[0] += BK; gAp[1] += BK;
        gBp[0] += BK; gBp[1] += BK; gBp[2] += BK; gBp[3] += BK;
        __syncthreads();

        half8 af[2][4], bf[2][2];
#pragma unroll
        for (int i = 0; i < 4; ++i) {
            int rbase = (i * 16 + fr) * BK;
            af[0][i] = *(const half8*)&As[rbase + slot0 * 8];
            af[1][i] = *(const half8*)&As[rbase + slot1 * 8];
        }
#pragma unroll
        for (int j = 0; j < 2; ++j) {
            int rbase = (wn + j * 16 + fr) * BK;
            bf[0][j] = *(const half8*)&Bs[rbase + slot0 * 8];
            bf[1][j] = *(const half8*)&Bs[rbase + slot1 * 8];
        }
#pragma unroll
        for (int s = 0; s < 2; ++s)
#pragma unroll
            for (int i = 0; i < 4; ++i)
#pragma unroll
                for (int j = 0; j < 2; ++j)
                    acc[i][j] = __builtin_amdgcn_mfma_f32_16x16x32_f16(
                        af[s][i], bf[s][j], acc[i][j], 0, 0, 0);
    }

    // epilogue: C/D layout col = lane&15 (N), row = (lane>>4)*4 + reg (M)
    const int col_base = bn * BN + wn + (lane & 15);
    const int row_base = bm * BM + ((lane >> 4) * 4);
#pragma unroll
    for (int j = 0; j < 2; ++j) {
        int n = col_base + j * 16;
        if (n >= 2 * LDIM) continue;           // N-pad region: discard
        int ri = (n >= LDIM) ? 1 : 0;
        int nn = n - ri * LDIM;
        int sym = nn / NSC;
        int jj = nn - sym * NSC;
        size_t colOff = (size_t)ri * (M_DIM * ROWLEN) + sym * FFT + sc[jj];
#pragma unroll
        for (int i = 0; i < 4; ++i) {
            int row0 = row_base + i * 16;
#pragma unroll
            for (int r = 0; r < 4; ++r) {
                out[colOff + (size_t)(row0 + r) * ROWLEN] = acc[i][j][r];
            }
        }
    }
}

// ---------------------------------------------------------------------------
extern "C" void kernel_launch(void* const* d_in, const int* in_sizes, int n_in,
                              void* d_out, int out_size, void* d_ws, size_t ws_size,
                              hipStream_t stream) {
    const float* xr = (const float*)d_in[0];
    const float* xi = (const float*)d_in[1];
    const float* Cr = (const float*)d_in[2];
    const float* Ci = (const float*)d_in[3];
    const int* sc   = (const int*)d_in[4];
    float* out = (float*)d_out;

    half_t* Ah = (half_t*)d_ws;                                      // 12.58 MB
    half_t* Wh = (half_t*)((char*)d_ws + (size_t)M_DIM * K_DIM * 2); // 18.87 MB

    prep_all<<<PA_BLOCKS + PW_BLOCKS + PG_BLOCKS, 256, 0, stream>>>(
        xr, xi, Cr, Ci, sc, Ah, Wh, out);

    dim3 grid(N_DIM / BN, M_DIM / BM);   // (24, 32) = 768 blocks
    gemm_scatter<<<grid, 256, 0, stream>>>(Ah, Wh, sc, out);
}